// Round 15
// baseline (281.463 us; speedup 1.0000x reference)
//
#include <hip/hip_runtime.h>
#include <stdint.h>

#define Hh 192
#define Ww 192
#define HW 36864            // 192*192
#define CROPW 38
#define CW2 1444            // 38*38
#define CROPOFF 77
#define NPTS 11552          // 8*38*38
#define NPAD 11776          // 92*128
#define NMT 92              // 128-row tiles
#define NCT 184             // 64-col tiles
#define NG 11               // col-tile groups
#define JPB 17              // col-tiles per group (last group gets 14)
#define NBLK (NG*NMT)       // 1012 blocks (~1 round at 4 blocks/CU)
#define SLABB 512           // 8 b * 64 channel-pairs
#define CROPB 304           // 38*8 crop blocks
#define BIGF 3.0e38f

typedef short bf16x8 __attribute__((ext_vector_type(8)));
typedef float f32x4 __attribute__((ext_vector_type(4)));
typedef uint32_t u32x4 __attribute__((ext_vector_type(4)));
typedef unsigned short ushort;

__device__ __forceinline__ ushort f2bf(float f) {
  uint32_t b = __float_as_uint(f);
  uint32_t r = b + 0x7fffu + ((b >> 16) & 1u);
  return (ushort)(r >> 16);
}
__device__ __forceinline__ float bf2f(ushort u) {
  return __uint_as_float(((uint32_t)u) << 16);
}

__device__ __forceinline__ void g2l16(const void* g, void* l) {
  __builtin_amdgcn_global_load_lds(
      (const __attribute__((address_space(1))) unsigned int*)g,
      (__attribute__((address_space(3))) unsigned int*)l, 16, 0, 0);
}

// ---- fused sampler: slab blocks (feat2->pB,d2) + crop blocks (feat1->aB,d1) ----
// (R12-proven, unchanged)
__global__ __launch_bounds__(1024) void fused_k(
    const float* __restrict__ feat1, const float* __restrict__ feat2,
    const float* __restrict__ aflow,
    ushort* __restrict__ aB, ushort* __restrict__ pB,
    float* __restrict__ d1, float* __restrict__ d2) {
  __shared__ __align__(16) uint32_t plane[HW];   // 144 KB (slab) / reused by crop
  int bid = blockIdx.x;
  int t = threadIdx.x;

  if (bid < SLABB) {
    // ---------------- slab: (b, channel-pair) ----------------
    int b = bid >> 6, c = (bid & 63) * 2;
    const float* srcA = feat2 + ((size_t)(b*128 + c)) * HW;
    const float* srcB = srcA + HW;
    #pragma unroll
    for (int k = 0; k < 9; ++k) {
      int i = (k*1024 + t) * 4;
      f32x4 va = *(const f32x4*)(srcA + i);
      f32x4 vb = *(const f32x4*)(srcB + i);
      u32x4 pk;
      #pragma unroll
      for (int j = 0; j < 4; ++j)
        pk[j] = (uint32_t)f2bf(va[j]) | ((uint32_t)f2bf(vb[j]) << 16);
      *(u32x4*)&plane[i] = pk;
    }
    __syncthreads();
    int pbase = b*CW2;
    #pragma unroll
    for (int it = 0; it < 2; ++it) {
      int p = it*1024 + t;
      if (p < CW2) {
        int r = p / CROPW, cx = p % CROPW;
        int y = CROPOFF + r, x = CROPOFF + cx;
        float ax = aflow[((b*2 + 0)*Hh + y)*Ww + x];
        float ay = aflow[((b*2 + 1)*Hh + y)*Ww + x];
        // replicate reference's normalize->denormalize round trip
        float gxn = ax * (2.0f/(Ww-1)) - 1.0f;
        float gyn = ay * (2.0f/(Hh-1)) - 1.0f;
        float gx = (gxn + 1.0f) * 0.5f * (Ww-1);
        float gy = (gyn + 1.0f) * 0.5f * (Hh-1);
        // clamp base cell to 190: gx==191 shifts weight to the x=191 tap
        int xi = min((int)floorf(gx), Ww-2);
        int yi = min((int)floorf(gy), Hh-2);
        float wx1 = gx - (float)xi, wx0 = 1.f - wx1;
        float wy1 = gy - (float)yi, wy0 = 1.f - wy1;
        int cell = yi*Ww + xi;
        uint32_t u00 = plane[cell];
        uint32_t u01 = plane[cell + 1];
        uint32_t u10 = plane[cell + Ww];
        uint32_t u11 = plane[cell + Ww + 1];
        float v0 = wy0*(wx0*bf2f((ushort)u00) + wx1*bf2f((ushort)u01))
                 + wy1*(wx0*bf2f((ushort)u10) + wx1*bf2f((ushort)u11));
        float v1 = wy0*(wx0*bf2f((ushort)(u00>>16)) + wx1*bf2f((ushort)(u01>>16)))
                 + wy1*(wx0*bf2f((ushort)(u10>>16)) + wx1*bf2f((ushort)(u11>>16)));
        ushort q0 = f2bf(v0), q1 = f2bf(v1);
        *(uint32_t*)&pB[(size_t)(pbase + p)*128 + c] = (uint32_t)q0 | ((uint32_t)q1 << 16);
        float f0 = bf2f(q0), f1 = bf2f(q1);
        atomicAdd(&d2[pbase + p], f0*f0 + f1*f1);
      }
    }
  } else if (bid < SLABB + CROPB) {
    // ---------------- crop row: feat1 -> aB (channel-last bf16) + d1 ----------
    ushort* lsh = (ushort*)plane;       // 38*136 ushorts
    int rb2 = bid - SLABB;
    int b = rb2 / CROPW, r = rb2 % CROPW;
    int y = CROPOFF + r;
    {
      int xo = t & 63, cg = t >> 6;     // 38 active lanes; 16 groups x 8 ch
      if (xo < CROPW) {
        const float* src = feat1 + ((size_t)b*128*HW) + (size_t)y*Ww + CROPOFF + xo;
        #pragma unroll
        for (int k = 0; k < 8; ++k) {
          int cc = cg + k*16;
          lsh[xo*136 + cc] = f2bf(src[(size_t)cc*HW]);
        }
      }
    }
    __syncthreads();
    int chunk = t & 7, p = t >> 3;      // 128 p-slots, 38 active
    if (p < CROPW) {
      int idx = b*CW2 + r*CROPW + p;
      ushort* dst = aB + (size_t)idx*128 + chunk*16;
      *(bf16x8*)dst       = *(const bf16x8*)&lsh[p*136 + chunk*16];
      *(bf16x8*)(dst + 8) = *(const bf16x8*)&lsh[p*136 + chunk*16 + 8];
      float s = 0.f;
      #pragma unroll
      for (int j = 0; j < 16; ++j) {
        float v = bf2f(lsh[p*136 + chunk*16 + j]);
        s += v*v;
      }
      s += __shfl_xor(s, 1); s += __shfl_xor(s, 2); s += __shfl_xor(s, 4);
      if (chunk == 0) d1[idx] = s;
    }
  } else {
    // ---------------- pad rows: zero aB/pB, d1=0, d2=big ----------------
    if (t < NPAD - NPTS) {
      int row = NPTS + t;
      u32x4 z = {0,0,0,0};
      #pragma unroll
      for (int c = 0; c < 8; ++c) {
        *(u32x4*)&aB[(size_t)row*128 + c*16] = z;
        *(u32x4*)&aB[(size_t)row*128 + c*16 + 8] = z;
        *(u32x4*)&pB[(size_t)row*128 + c*16] = z;
        *(u32x4*)&pB[(size_t)row*128 + c*16 + 8] = z;
      }
      d1[row] = 0.f;
      d2[row] = 1e30f;
    }
  }
}

// ---- persistent fused GEMM: BN=64, 4 blocks/CU (16 waves/CU) ----------------
// 256 thr, 4 waves = 4 N-strips of 16 cols; block tile 128M x 64N; B tile
// 16 KB, double-buffered (32 KB LDS). __launch_bounds__(256,4) pins VGPR<=128
// so occupancy doubles vs R12 (the m97-structure overlap lever, m114).
// Swapped MFMA: anchor index in lane&15. Swizzle (row&7)<<4 both-sides.
__global__ __launch_bounds__(256, 4) void gemmp_k(
    const ushort* __restrict__ aB, const ushort* __restrict__ pB,
    const float* __restrict__ d1, const float* __restrict__ d2,
    float* __restrict__ pos, float* __restrict__ pmin) {
  __shared__ __align__(16) ushort lB[2][64*128];    // 2 x 16 KB

  // m204 bijective chunked XCD swizzle: nwg=1012, q=126, r=4
  int bid = blockIdx.x;
  int xcd = bid & 7, kk = bid >> 3;
  int start = (xcd < 4) ? xcd*127 : 508 + (xcd-4)*126;
  int L = start + kk;
  int g = L / NMT, tM = L % NMT;
  int j0 = g * JPB;
  int jn = (NCT - j0 < JPB) ? (NCT - j0) : JPB;

  int tid = threadIdx.x;
  int rowg = tid >> 4, cb = (tid & 15) << 4;   // staging: 16 row-grp x 16B
  int w = tid >> 6, l = tid & 63;
  int wc = w;                           // 4 N-strips of 16 cols
  int lcol = l & 15, hq = l >> 4, rb = hq << 2;
  int rsw = (lcol & 7) << 4;

  {  // stage B0 (swizzled source, linear dest): 64 rows x 256 B, 4 rounds
    const char* gB = (const char*)pB + (size_t)j0 * 64 * 256;
    #pragma unroll
    for (int rnd = 0; rnd < 4; ++rnd) {
      int row = rnd*16 + rowg;
      g2l16(gB + row*256 + (cb ^ ((row&7)<<4)), (char*)lB[0] + row*256 + cb);
    }
  }

  // hoist A fragments: row = tM*128 + ma*16 + lcol (compiler may demote to L2
  // reloads under the 128-VGPR cap -- acceptable, A is L2-resident)
  bf16x8 aF[32];                        // [ma*4+ks]
  {
    const char* gA = (const char*)aB + ((size_t)(tM*128 + lcol))*256 + hq*16;
    #pragma unroll
    for (int ma = 0; ma < 8; ++ma)
      #pragma unroll
      for (int ks = 0; ks < 4; ++ks)
        aF[ma*4+ks] = *(const bf16x8*)(gA + ma*16*256 + ks*64);
  }
  __syncthreads();   // drains vmcnt (B0 + aF)

  float mPart[8] = {BIGF,BIGF,BIGF,BIGF,BIGF,BIGF,BIGF,BIGF};

  for (int it = 0; it < jn; ++it) {
    int j = j0 + it;
    if (it + 1 < jn) {  // prefetch next B into alt buffer (overlaps compute)
      const char* gB = (const char*)pB + (size_t)(j+1) * 64 * 256;
      char* dst = (char*)lB[(it+1) & 1];
      #pragma unroll
      for (int rnd = 0; rnd < 4; ++rnd) {
        int row = rnd*16 + rowg;
        g2l16(gB + row*256 + (cb ^ ((row&7)<<4)), dst + row*256 + cb);
      }
    }
    // d2v early: latency hides under the MFMA loop below
    f32x4 d2v = *(const f32x4*)&d2[j*64 + wc*16 + rb];

    const char* bufB = (const char*)lB[it & 1];
    f32x4 acc[8] = {};                  // acc[ma]
    #pragma unroll
    for (int ks = 0; ks < 4; ++ks) {
      int cbase = ks*64 + (hq << 4);
      bf16x8 bF = *(const bf16x8*)(bufB + (wc*16 + lcol)*256 + (cbase ^ rsw));
      #pragma unroll
      for (int ma = 0; ma < 8; ++ma)
        acc[ma] = __builtin_amdgcn_mfma_f32_16x16x32_bf16(bF, aF[ma*4+ks], acc[ma], 0, 0, 0);
    }

    // epilogue in t-space: t = d2[col] - 2*dot; min accumulates in mPart regs
    if ((j >> 1) != tM) {               // non-diagonal col-tile (uniform branch)
      #pragma unroll
      for (int ma = 0; ma < 8; ++ma)
        #pragma unroll
        for (int reg = 0; reg < 4; ++reg)
          mPart[ma] = fminf(mPart[ma], fmaf(-2.f, acc[ma][reg], d2v[reg]));
    } else {                            // diagonal-overlapping tile
      #pragma unroll
      for (int ma = 0; ma < 8; ++ma) {
        int gi = tM*128 + ma*16 + lcol;
        #pragma unroll
        for (int reg = 0; reg < 4; ++reg) {
          int gj = j*64 + wc*16 + rb + reg;
          float t = fmaf(-2.f, acc[ma][reg], d2v[reg]);
          if (gi == gj)
            pos[gi] = sqrtf(fmaxf(d1[gi] + t, 0.f) + 1e-6f) + 1e-8f;
          else
            mPart[ma] = fminf(mPart[ma], t);
        }
      }
    }
    __syncthreads();                    // next buffer staged + all reads done
  }

  // final reduce: over hq via shuffles, over the 4 col-strip waves via LDS
  #pragma unroll
  for (int ma = 0; ma < 8; ++ma) {
    float u = mPart[ma];
    u = fminf(u, __shfl_xor(u, 16));
    u = fminf(u, __shfl_xor(u, 32));
    mPart[ma] = u;
  }
  __syncthreads();
  float* sm = (float*)lB;               // scratch [4][128]
  if (hq == 0) {
    #pragma unroll
    for (int ma = 0; ma < 8; ++ma)
      sm[wc*128 + ma*16 + lcol] = mPart[ma];
  }
  __syncthreads();
  if (tid < 128) {
    int row = tM*128 + tid;
    float u = fminf(fminf(sm[tid], sm[128 + tid]),
                    fminf(sm[256 + tid], sm[384 + tid]));
    pmin[g*NPAD + row] = sqrtf(fmaxf(d1[row] + u, 0.f) + 1e-6f) + 1e-8f;
  }
}

// -------- finalize: min over group partials (+ diag+10 cand), mean relu --------
__global__ __launch_bounds__(1024) void fin_k(const float* __restrict__ pos,
                                              const float* __restrict__ pmin,
                                              float* __restrict__ out) {
  float s = 0.f;
  for (int i = threadIdx.x*4; i < NPTS; i += 4096) {
    f32x4 p = *(const f32x4*)&pos[i];
    f32x4 mn;
    #pragma unroll
    for (int jj = 0; jj < 4; ++jj) mn[jj] = p[jj] + 10.f;
    #pragma unroll
    for (int gg = 0; gg < NG; ++gg) {
      f32x4 pm = *(const f32x4*)&pmin[gg*NPAD + i];
      #pragma unroll
      for (int jj = 0; jj < 4; ++jj) mn[jj] = fminf(mn[jj], pm[jj]);
    }
    #pragma unroll
    for (int jj = 0; jj < 4; ++jj)
      s += fmaxf(1.0f + p[jj] - mn[jj], 0.f);
  }
  for (int off = 1; off < 64; off <<= 1) s += __shfl_xor(s, off);
  __shared__ float red[16];
  if ((threadIdx.x & 63) == 0) red[threadIdx.x >> 6] = s;
  __syncthreads();
  if (threadIdx.x == 0) {
    float t = 0.f;
    #pragma unroll
    for (int k = 0; k < 16; ++k) t += red[k];
    out[0] = t / (float)NPTS;
  }
}

extern "C" void kernel_launch(void* const* d_in, const int* in_sizes, int n_in,
                              void* d_out, int out_size, void* d_ws, size_t ws_size,
                              hipStream_t stream) {
  const float* feat1 = (const float*)d_in[0];
  const float* feat2 = (const float*)d_in[1];
  const float* aflow = (const float*)d_in[2];

  char* ws = (char*)d_ws;
  ushort* aB = (ushort*)ws;                                   // NPAD*128 bf16
  ushort* pB = aB + (size_t)NPAD * 128;                       // NPAD*128 bf16
  float*  d1 = (float*)(pB + (size_t)NPAD * 128);             // NPAD f32
  float*  d2 = d1 + NPAD;
  float*  pos = d2 + NPAD;
  float*  pmin = pos + NPAD;                                  // NG*NPAD f32

  hipMemsetAsync(d2, 0, NPTS * sizeof(float), stream);        // slab atomics base
  hipLaunchKernelGGL(fused_k, dim3(SLABB + CROPB + 1), dim3(1024), 0, stream,
                     feat1, feat2, aflow, aB, pB, d1, d2);
  hipLaunchKernelGGL(gemmp_k, dim3(NBLK), dim3(256), 0, stream,
                     aB, pB, d1, d2, pos, pmin);
  hipLaunchKernelGGL(fin_k, dim3(1), dim3(1024), 0, stream,
                     pos, pmin, (float*)d_out);
}

// Round 16
// 122.931 us; speedup vs baseline: 2.2896x; 2.2896x over previous
//
#include <hip/hip_runtime.h>
#include <stdint.h>

#define Hh 192
#define Ww 192
#define HW 36864            // 192*192
#define CROPW 38
#define CW2 1444            // 38*38
#define CROPOFF 77
#define NPTS 11552          // 8*38*38
#define NPAD 11776          // 92*128
#define NMT 92              // 128-row tiles
#define NCT 92              // 128-col tiles
#define NG 5                // col-tile groups
#define JPB 19              // col-tiles per group (last group gets 16)
#define NBLK (NG*NMT)       // 460 blocks
#define SLABB 512           // 8 b * 64 channel-pairs
#define CROPB 304           // 38*8 crop blocks
#define BIGF 3.0e38f

typedef short bf16x8 __attribute__((ext_vector_type(8)));
typedef float f32x4 __attribute__((ext_vector_type(4)));
typedef uint32_t u32x4 __attribute__((ext_vector_type(4)));
typedef unsigned short ushort;

__device__ __forceinline__ ushort f2bf(float f) {
  uint32_t b = __float_as_uint(f);
  uint32_t r = b + 0x7fffu + ((b >> 16) & 1u);
  return (ushort)(r >> 16);
}
__device__ __forceinline__ float bf2f(ushort u) {
  return __uint_as_float(((uint32_t)u) << 16);
}

__device__ __forceinline__ void g2l16(const void* g, void* l) {
  __builtin_amdgcn_global_load_lds(
      (const __attribute__((address_space(1))) unsigned int*)g,
      (__attribute__((address_space(3))) unsigned int*)l, 16, 0, 0);
}

// ---- fused sampler: slab blocks (feat2->pB,d2) + crop blocks (feat1->aB,d1) ----
// (R12-proven, unchanged)
__global__ __launch_bounds__(1024) void fused_k(
    const float* __restrict__ feat1, const float* __restrict__ feat2,
    const float* __restrict__ aflow,
    ushort* __restrict__ aB, ushort* __restrict__ pB,
    float* __restrict__ d1, float* __restrict__ d2) {
  __shared__ __align__(16) uint32_t plane[HW];   // 144 KB (slab) / reused by crop
  int bid = blockIdx.x;
  int t = threadIdx.x;

  if (bid < SLABB) {
    // ---------------- slab: (b, channel-pair) ----------------
    int b = bid >> 6, c = (bid & 63) * 2;
    const float* srcA = feat2 + ((size_t)(b*128 + c)) * HW;
    const float* srcB = srcA + HW;
    #pragma unroll
    for (int k = 0; k < 9; ++k) {
      int i = (k*1024 + t) * 4;
      f32x4 va = *(const f32x4*)(srcA + i);
      f32x4 vb = *(const f32x4*)(srcB + i);
      u32x4 pk;
      #pragma unroll
      for (int j = 0; j < 4; ++j)
        pk[j] = (uint32_t)f2bf(va[j]) | ((uint32_t)f2bf(vb[j]) << 16);
      *(u32x4*)&plane[i] = pk;
    }
    __syncthreads();
    int pbase = b*CW2;
    #pragma unroll
    for (int it = 0; it < 2; ++it) {
      int p = it*1024 + t;
      if (p < CW2) {
        int r = p / CROPW, cx = p % CROPW;
        int y = CROPOFF + r, x = CROPOFF + cx;
        float ax = aflow[((b*2 + 0)*Hh + y)*Ww + x];
        float ay = aflow[((b*2 + 1)*Hh + y)*Ww + x];
        // replicate reference's normalize->denormalize round trip
        float gxn = ax * (2.0f/(Ww-1)) - 1.0f;
        float gyn = ay * (2.0f/(Hh-1)) - 1.0f;
        float gx = (gxn + 1.0f) * 0.5f * (Ww-1);
        float gy = (gyn + 1.0f) * 0.5f * (Hh-1);
        // clamp base cell to 190: gx==191 shifts weight to the x=191 tap
        int xi = min((int)floorf(gx), Ww-2);
        int yi = min((int)floorf(gy), Hh-2);
        float wx1 = gx - (float)xi, wx0 = 1.f - wx1;
        float wy1 = gy - (float)yi, wy0 = 1.f - wy1;
        int cell = yi*Ww + xi;
        uint32_t u00 = plane[cell];
        uint32_t u01 = plane[cell + 1];
        uint32_t u10 = plane[cell + Ww];
        uint32_t u11 = plane[cell + Ww + 1];
        float v0 = wy0*(wx0*bf2f((ushort)u00) + wx1*bf2f((ushort)u01))
                 + wy1*(wx0*bf2f((ushort)u10) + wx1*bf2f((ushort)u11));
        float v1 = wy0*(wx0*bf2f((ushort)(u00>>16)) + wx1*bf2f((ushort)(u01>>16)))
                 + wy1*(wx0*bf2f((ushort)(u10>>16)) + wx1*bf2f((ushort)(u11>>16)));
        ushort q0 = f2bf(v0), q1 = f2bf(v1);
        *(uint32_t*)&pB[(size_t)(pbase + p)*128 + c] = (uint32_t)q0 | ((uint32_t)q1 << 16);
        float f0 = bf2f(q0), f1 = bf2f(q1);
        atomicAdd(&d2[pbase + p], f0*f0 + f1*f1);
      }
    }
  } else if (bid < SLABB + CROPB) {
    // ---------------- crop row: feat1 -> aB (channel-last bf16) + d1 ----------
    ushort* lsh = (ushort*)plane;       // 38*136 ushorts
    int rb2 = bid - SLABB;
    int b = rb2 / CROPW, r = rb2 % CROPW;
    int y = CROPOFF + r;
    {
      int xo = t & 63, cg = t >> 6;     // 38 active lanes; 16 groups x 8 ch
      if (xo < CROPW) {
        const float* src = feat1 + ((size_t)b*128*HW) + (size_t)y*Ww + CROPOFF + xo;
        #pragma unroll
        for (int k = 0; k < 8; ++k) {
          int cc = cg + k*16;
          lsh[xo*136 + cc] = f2bf(src[(size_t)cc*HW]);
        }
      }
    }
    __syncthreads();
    int chunk = t & 7, p = t >> 3;      // 128 p-slots, 38 active
    if (p < CROPW) {
      int idx = b*CW2 + r*CROPW + p;
      ushort* dst = aB + (size_t)idx*128 + chunk*16;
      *(bf16x8*)dst       = *(const bf16x8*)&lsh[p*136 + chunk*16];
      *(bf16x8*)(dst + 8) = *(const bf16x8*)&lsh[p*136 + chunk*16 + 8];
      float s = 0.f;
      #pragma unroll
      for (int j = 0; j < 16; ++j) {
        float v = bf2f(lsh[p*136 + chunk*16 + j]);
        s += v*v;
      }
      s += __shfl_xor(s, 1); s += __shfl_xor(s, 2); s += __shfl_xor(s, 4);
      if (chunk == 0) d1[idx] = s;
    }
  } else {
    // ---------------- pad rows: zero aB/pB, d1=0, d2=big ----------------
    if (t < NPAD - NPTS) {
      int row = NPTS + t;
      u32x4 z = {0,0,0,0};
      #pragma unroll
      for (int c = 0; c < 8; ++c) {
        *(u32x4*)&aB[(size_t)row*128 + c*16] = z;
        *(u32x4*)&aB[(size_t)row*128 + c*16 + 8] = z;
        *(u32x4*)&pB[(size_t)row*128 + c*16] = z;
        *(u32x4*)&pB[(size_t)row*128 + c*16 + 8] = z;
      }
      d1[row] = 0.f;
      d2[row] = 1e30f;
    }
  }
}

// ---- persistent fused GEMM: 128x128 tile, 8 waves (2mh x 4wc), 16 waves/CU ---
// Same block tile / LDS (2x32KB -> 2 blocks/CU) / staging / swizzle as R12;
// 512 threads halve per-wave registers (aF[16]+acc[2][4] ~ 125 VGPR) so the
// 128-VGPR bin fits -> 16 waves/CU (2x R12) for latency hiding (m114).
// Swapped MFMA: anchor index in lane&15. Swizzle (row&7)<<4 both-sides.
__global__ __launch_bounds__(512, 4) void gemmp_k(
    const ushort* __restrict__ aB, const ushort* __restrict__ pB,
    const float* __restrict__ d1, const float* __restrict__ d2,
    float* __restrict__ pos, float* __restrict__ pmin) {
  __shared__ __align__(16) ushort lB[2][128*128];   // 2 x 32 KB

  // m204 bijective chunked XCD swizzle: nwg=460, q=57, r=4
  int bid = blockIdx.x;
  int xcd = bid & 7, kk = bid >> 3;
  int start = (xcd < 4) ? xcd*58 : 232 + (xcd-4)*57;
  int L = start + kk;
  int g = L / NMT, tM = L % NMT;
  int j0 = g * JPB;
  int jn = (NCT - j0 < JPB) ? (NCT - j0) : JPB;

  int tid = threadIdx.x;
  int rowg = tid >> 4, cb = (tid & 15) << 4;   // staging: 32 row-grp x 16B
  int w = tid >> 6, l = tid & 63;
  int mh = w >> 2, wc = w & 3;          // wave tile 64M (mh) x 32N (wc)
  int lcol = l & 15, hq = l >> 4, rb = hq << 2;
  int rsw = (lcol & 7) << 4;

  {  // stage B0 (swizzled source, linear dest): 128 rows x 256 B, 4 rounds
    const char* gB = (const char*)pB + (size_t)j0 * 128 * 256;
    #pragma unroll
    for (int rnd = 0; rnd < 4; ++rnd) {
      int row = rnd*32 + rowg;
      g2l16(gB + row*256 + (cb ^ ((row&7)<<4)), (char*)lB[0] + row*256 + cb);
    }
  }

  // hoist A fragments once: rows = tM*128 + mh*64 + ma*16 + lcol (ma=0..3)
  // (compiler may demote some to per-iter L2 reloads -- proven OK, R12/R14)
  bf16x8 aF[16];                        // [ma*4+ks], 64 VGPR
  {
    const char* gA = (const char*)aB + ((size_t)(tM*128 + mh*64 + lcol))*256 + hq*16;
    #pragma unroll
    for (int ma = 0; ma < 4; ++ma)
      #pragma unroll
      for (int ks = 0; ks < 4; ++ks)
        aF[ma*4+ks] = *(const bf16x8*)(gA + ma*16*256 + ks*64);
  }
  __syncthreads();   // drains vmcnt (B0 + aF)

  float mPart[4] = {BIGF, BIGF, BIGF, BIGF};

  for (int it = 0; it < jn; ++it) {
    int j = j0 + it;
    if (it + 1 < jn) {  // prefetch next B into alt buffer (overlaps compute)
      const char* gB = (const char*)pB + (size_t)(j+1) * 128 * 256;
      char* dst = (char*)lB[(it+1) & 1];
      #pragma unroll
      for (int rnd = 0; rnd < 4; ++rnd) {
        int row = rnd*32 + rowg;
        g2l16(gB + row*256 + (cb ^ ((row&7)<<4)), dst + row*256 + cb);
      }
    }
    // d2v early: latency hides under the MFMA loop below
    f32x4 d2v[2];
    #pragma unroll
    for (int np = 0; np < 2; ++np)
      d2v[np] = *(const f32x4*)&d2[j*128 + wc*32 + np*16 + rb];

    const char* bufB = (const char*)lB[it & 1];
    f32x4 acc[2][4] = {};               // acc[np][ma]
    #pragma unroll
    for (int ks = 0; ks < 4; ++ks) {
      int cbase = ks*64 + (hq << 4);
      bf16x8 bF[2];
      #pragma unroll
      for (int np = 0; np < 2; ++np)
        bF[np] = *(const bf16x8*)(bufB + (wc*32 + np*16 + lcol)*256 + (cbase ^ rsw));
      #pragma unroll
      for (int np = 0; np < 2; ++np)
        #pragma unroll
        for (int ma = 0; ma < 4; ++ma)
          acc[np][ma] = __builtin_amdgcn_mfma_f32_16x16x32_bf16(bF[np], aF[ma*4+ks], acc[np][ma], 0, 0, 0);
    }

    // epilogue in t-space: t = d2[col] - 2*dot; min accumulates in mPart regs
    if (j != tM) {                      // non-diagonal col-tile (uniform branch)
      #pragma unroll
      for (int ma = 0; ma < 4; ++ma)
        #pragma unroll
        for (int np = 0; np < 2; ++np)
          #pragma unroll
          for (int reg = 0; reg < 4; ++reg)
            mPart[ma] = fminf(mPart[ma], fmaf(-2.f, acc[np][ma][reg], d2v[np][reg]));
    } else {                            // diagonal tile (once per block)
      #pragma unroll
      for (int ma = 0; ma < 4; ++ma) {
        int gi = tM*128 + mh*64 + ma*16 + lcol;
        #pragma unroll
        for (int np = 0; np < 2; ++np)
          #pragma unroll
          for (int reg = 0; reg < 4; ++reg) {
            int gj = j*128 + wc*32 + np*16 + rb + reg;
            float t = fmaf(-2.f, acc[np][ma][reg], d2v[np][reg]);
            if (gi == gj)
              pos[gi] = sqrtf(fmaxf(d1[gi] + t, 0.f) + 1e-6f) + 1e-8f;
            else
              mPart[ma] = fminf(mPart[ma], t);
          }
      }
    }
    __syncthreads();                    // next buffer staged + all reads done
  }

  // final reduce: over hq via shuffles, over the 4 wc waves via LDS scratch
  #pragma unroll
  for (int ma = 0; ma < 4; ++ma) {
    float u = mPart[ma];
    u = fminf(u, __shfl_xor(u, 16));
    u = fminf(u, __shfl_xor(u, 32));
    mPart[ma] = u;
  }
  __syncthreads();
  float* sm = (float*)lB;               // scratch [8][64]
  if (hq == 0) {
    #pragma unroll
    for (int ma = 0; ma < 4; ++ma)
      sm[(mh*4 + wc)*64 + ma*16 + lcol] = mPart[ma];
  }
  __syncthreads();
  if (tid < 128) {
    int mh2 = tid >> 6, rloc = tid & 63;
    float u = fminf(fminf(sm[(mh2*4+0)*64 + rloc], sm[(mh2*4+1)*64 + rloc]),
                    fminf(sm[(mh2*4+2)*64 + rloc], sm[(mh2*4+3)*64 + rloc]));
    int row = tM*128 + tid;
    pmin[g*NPAD + row] = sqrtf(fmaxf(d1[row] + u, 0.f) + 1e-6f) + 1e-8f;
  }
}

// -------- finalize: min over group partials (+ diag+10 cand), mean relu --------
__global__ __launch_bounds__(1024) void fin_k(const float* __restrict__ pos,
                                              const float* __restrict__ pmin,
                                              float* __restrict__ out) {
  float s = 0.f;
  for (int i = threadIdx.x*4; i < NPTS; i += 4096) {
    f32x4 p = *(const f32x4*)&pos[i];
    f32x4 mn;
    #pragma unroll
    for (int jj = 0; jj < 4; ++jj) mn[jj] = p[jj] + 10.f;
    #pragma unroll
    for (int gg = 0; gg < NG; ++gg) {
      f32x4 pm = *(const f32x4*)&pmin[gg*NPAD + i];
      #pragma unroll
      for (int jj = 0; jj < 4; ++jj) mn[jj] = fminf(mn[jj], pm[jj]);
    }
    #pragma unroll
    for (int jj = 0; jj < 4; ++jj)
      s += fmaxf(1.0f + p[jj] - mn[jj], 0.f);
  }
  for (int off = 1; off < 64; off <<= 1) s += __shfl_xor(s, off);
  __shared__ float red[16];
  if ((threadIdx.x & 63) == 0) red[threadIdx.x >> 6] = s;
  __syncthreads();
  if (threadIdx.x == 0) {
    float t = 0.f;
    #pragma unroll
    for (int k = 0; k < 16; ++k) t += red[k];
    out[0] = t / (float)NPTS;
  }
}

extern "C" void kernel_launch(void* const* d_in, const int* in_sizes, int n_in,
                              void* d_out, int out_size, void* d_ws, size_t ws_size,
                              hipStream_t stream) {
  const float* feat1 = (const float*)d_in[0];
  const float* feat2 = (const float*)d_in[1];
  const float* aflow = (const float*)d_in[2];

  char* ws = (char*)d_ws;
  ushort* aB = (ushort*)ws;                                   // NPAD*128 bf16
  ushort* pB = aB + (size_t)NPAD * 128;                       // NPAD*128 bf16
  float*  d1 = (float*)(pB + (size_t)NPAD * 128);             // NPAD f32
  float*  d2 = d1 + NPAD;
  float*  pos = d2 + NPAD;
  float*  pmin = pos + NPAD;                                  // NG*NPAD f32

  hipMemsetAsync(d2, 0, NPTS * sizeof(float), stream);        // slab atomics base
  hipLaunchKernelGGL(fused_k, dim3(SLABB + CROPB + 1), dim3(1024), 0, stream,
                     feat1, feat2, aflow, aB, pB, d1, d2);
  hipLaunchKernelGGL(gemmp_k, dim3(NBLK), dim3(512), 0, stream,
                     aB, pB, d1, d2, pos, pmin);
  hipLaunchKernelGGL(fin_k, dim3(1), dim3(1024), 0, stream,
                     pos, pmin, (float*)d_out);
}

// Round 17
// 103.056 us; speedup vs baseline: 2.7312x; 1.1929x over previous
//
#include <hip/hip_runtime.h>
#include <stdint.h>

#define Hh 192
#define Ww 192
#define HW 36864            // 192*192
#define CROPW 38
#define CW2 1444            // 38*38
#define CROPOFF 77
#define NPTS 11552          // 8*38*38
#define NPAD 11776          // 92*128
#define NMT 92              // 128-row tiles
#define NCT 92              // 128-col tiles
#define NG 5                // col-tile groups
#define JPB 19              // col-tiles per group (last group gets 16)
#define NBLK (NG*NMT)       // 460 blocks
#define SLABB 512           // 8 b * 64 channel-pairs
#define CROPB 304           // 38*8 crop blocks
#define BIGF 3.0e38f

typedef short bf16x8 __attribute__((ext_vector_type(8)));
typedef float f32x4 __attribute__((ext_vector_type(4)));
typedef uint32_t u32x4 __attribute__((ext_vector_type(4)));
typedef unsigned short ushort;

__device__ __forceinline__ ushort f2bf(float f) {
  uint32_t b = __float_as_uint(f);
  uint32_t r = b + 0x7fffu + ((b >> 16) & 1u);
  return (ushort)(r >> 16);
}
__device__ __forceinline__ float bf2f(ushort u) {
  return __uint_as_float(((uint32_t)u) << 16);
}

__device__ __forceinline__ void g2l16(const void* g, void* l) {
  __builtin_amdgcn_global_load_lds(
      (const __attribute__((address_space(1))) unsigned int*)g,
      (__attribute__((address_space(3))) unsigned int*)l, 16, 0, 0);
}

// ---- fused sampler: slab blocks (feat2->pB,d2) + crop blocks (feat1->aB,d1) ----
// (R12-proven, unchanged)
__global__ __launch_bounds__(1024) void fused_k(
    const float* __restrict__ feat1, const float* __restrict__ feat2,
    const float* __restrict__ aflow,
    ushort* __restrict__ aB, ushort* __restrict__ pB,
    float* __restrict__ d1, float* __restrict__ d2) {
  __shared__ __align__(16) uint32_t plane[HW];   // 144 KB (slab) / reused by crop
  int bid = blockIdx.x;
  int t = threadIdx.x;

  if (bid < SLABB) {
    // ---------------- slab: (b, channel-pair) ----------------
    int b = bid >> 6, c = (bid & 63) * 2;
    const float* srcA = feat2 + ((size_t)(b*128 + c)) * HW;
    const float* srcB = srcA + HW;
    #pragma unroll
    for (int k = 0; k < 9; ++k) {
      int i = (k*1024 + t) * 4;
      f32x4 va = *(const f32x4*)(srcA + i);
      f32x4 vb = *(const f32x4*)(srcB + i);
      u32x4 pk;
      #pragma unroll
      for (int j = 0; j < 4; ++j)
        pk[j] = (uint32_t)f2bf(va[j]) | ((uint32_t)f2bf(vb[j]) << 16);
      *(u32x4*)&plane[i] = pk;
    }
    __syncthreads();
    int pbase = b*CW2;
    #pragma unroll
    for (int it = 0; it < 2; ++it) {
      int p = it*1024 + t;
      if (p < CW2) {
        int r = p / CROPW, cx = p % CROPW;
        int y = CROPOFF + r, x = CROPOFF + cx;
        float ax = aflow[((b*2 + 0)*Hh + y)*Ww + x];
        float ay = aflow[((b*2 + 1)*Hh + y)*Ww + x];
        // replicate reference's normalize->denormalize round trip
        float gxn = ax * (2.0f/(Ww-1)) - 1.0f;
        float gyn = ay * (2.0f/(Hh-1)) - 1.0f;
        float gx = (gxn + 1.0f) * 0.5f * (Ww-1);
        float gy = (gyn + 1.0f) * 0.5f * (Hh-1);
        // clamp base cell to 190: gx==191 shifts weight to the x=191 tap
        int xi = min((int)floorf(gx), Ww-2);
        int yi = min((int)floorf(gy), Hh-2);
        float wx1 = gx - (float)xi, wx0 = 1.f - wx1;
        float wy1 = gy - (float)yi, wy0 = 1.f - wy1;
        int cell = yi*Ww + xi;
        uint32_t u00 = plane[cell];
        uint32_t u01 = plane[cell + 1];
        uint32_t u10 = plane[cell + Ww];
        uint32_t u11 = plane[cell + Ww + 1];
        float v0 = wy0*(wx0*bf2f((ushort)u00) + wx1*bf2f((ushort)u01))
                 + wy1*(wx0*bf2f((ushort)u10) + wx1*bf2f((ushort)u11));
        float v1 = wy0*(wx0*bf2f((ushort)(u00>>16)) + wx1*bf2f((ushort)(u01>>16)))
                 + wy1*(wx0*bf2f((ushort)(u10>>16)) + wx1*bf2f((ushort)(u11>>16)));
        ushort q0 = f2bf(v0), q1 = f2bf(v1);
        *(uint32_t*)&pB[(size_t)(pbase + p)*128 + c] = (uint32_t)q0 | ((uint32_t)q1 << 16);
        float f0 = bf2f(q0), f1 = bf2f(q1);
        atomicAdd(&d2[pbase + p], f0*f0 + f1*f1);
      }
    }
  } else if (bid < SLABB + CROPB) {
    // ---------------- crop row: feat1 -> aB (channel-last bf16) + d1 ----------
    ushort* lsh = (ushort*)plane;       // 38*136 ushorts
    int rb2 = bid - SLABB;
    int b = rb2 / CROPW, r = rb2 % CROPW;
    int y = CROPOFF + r;
    {
      int xo = t & 63, cg = t >> 6;     // 38 active lanes; 16 groups x 8 ch
      if (xo < CROPW) {
        const float* src = feat1 + ((size_t)b*128*HW) + (size_t)y*Ww + CROPOFF + xo;
        #pragma unroll
        for (int k = 0; k < 8; ++k) {
          int cc = cg + k*16;
          lsh[xo*136 + cc] = f2bf(src[(size_t)cc*HW]);
        }
      }
    }
    __syncthreads();
    int chunk = t & 7, p = t >> 3;      // 128 p-slots, 38 active
    if (p < CROPW) {
      int idx = b*CW2 + r*CROPW + p;
      ushort* dst = aB + (size_t)idx*128 + chunk*16;
      *(bf16x8*)dst       = *(const bf16x8*)&lsh[p*136 + chunk*16];
      *(bf16x8*)(dst + 8) = *(const bf16x8*)&lsh[p*136 + chunk*16 + 8];
      float s = 0.f;
      #pragma unroll
      for (int j = 0; j < 16; ++j) {
        float v = bf2f(lsh[p*136 + chunk*16 + j]);
        s += v*v;
      }
      s += __shfl_xor(s, 1); s += __shfl_xor(s, 2); s += __shfl_xor(s, 4);
      if (chunk == 0) d1[idx] = s;
    }
  } else {
    // ---------------- pad rows: zero aB/pB, d1=0, d2=big ----------------
    if (t < NPAD - NPTS) {
      int row = NPTS + t;
      u32x4 z = {0,0,0,0};
      #pragma unroll
      for (int c = 0; c < 8; ++c) {
        *(u32x4*)&aB[(size_t)row*128 + c*16] = z;
        *(u32x4*)&aB[(size_t)row*128 + c*16 + 8] = z;
        *(u32x4*)&pB[(size_t)row*128 + c*16] = z;
        *(u32x4*)&pB[(size_t)row*128 + c*16 + 8] = z;
      }
      d1[row] = 0.f;
      d2[row] = 1e30f;
    }
  }
}

// ---- persistent fused GEMM: 128x128 tile, 8 waves (2mh x 4wc), 16 waves/CU ---
// R16 body unchanged; ONLY the launch bound differs: (512,2) -> VGPR cap 128
// (hipcc cap ~ 256/arg: arg2->128 proven R12, arg4->64 broke R15/R16).
// LDS 2x32KB -> 2 blocks/CU x 8 waves = 16 waves/CU; VGPR 128 bin also allows
// 16 waves/CU -- occupancy doubling vs R12 without the VGPR cliff.
__global__ __launch_bounds__(512, 2) void gemmp_k(
    const ushort* __restrict__ aB, const ushort* __restrict__ pB,
    const float* __restrict__ d1, const float* __restrict__ d2,
    float* __restrict__ pos, float* __restrict__ pmin) {
  __shared__ __align__(16) ushort lB[2][128*128];   // 2 x 32 KB

  // m204 bijective chunked XCD swizzle: nwg=460, q=57, r=4
  int bid = blockIdx.x;
  int xcd = bid & 7, kk = bid >> 3;
  int start = (xcd < 4) ? xcd*58 : 232 + (xcd-4)*57;
  int L = start + kk;
  int g = L / NMT, tM = L % NMT;
  int j0 = g * JPB;
  int jn = (NCT - j0 < JPB) ? (NCT - j0) : JPB;

  int tid = threadIdx.x;
  int rowg = tid >> 4, cb = (tid & 15) << 4;   // staging: 32 row-grp x 16B
  int w = tid >> 6, l = tid & 63;
  int mh = w >> 2, wc = w & 3;          // wave tile 64M (mh) x 32N (wc)
  int lcol = l & 15, hq = l >> 4, rb = hq << 2;
  int rsw = (lcol & 7) << 4;

  {  // stage B0 (swizzled source, linear dest): 128 rows x 256 B, 4 rounds
    const char* gB = (const char*)pB + (size_t)j0 * 128 * 256;
    #pragma unroll
    for (int rnd = 0; rnd < 4; ++rnd) {
      int row = rnd*32 + rowg;
      g2l16(gB + row*256 + (cb ^ ((row&7)<<4)), (char*)lB[0] + row*256 + cb);
    }
  }

  // hoist A fragments once: rows = tM*128 + mh*64 + ma*16 + lcol (ma=0..3)
  // (compiler may demote some to per-iter L2 reloads -- proven OK, R12)
  bf16x8 aF[16];                        // [ma*4+ks], 64 VGPR
  {
    const char* gA = (const char*)aB + ((size_t)(tM*128 + mh*64 + lcol))*256 + hq*16;
    #pragma unroll
    for (int ma = 0; ma < 4; ++ma)
      #pragma unroll
      for (int ks = 0; ks < 4; ++ks)
        aF[ma*4+ks] = *(const bf16x8*)(gA + ma*16*256 + ks*64);
  }
  __syncthreads();   // drains vmcnt (B0 + aF)

  float mPart[4] = {BIGF, BIGF, BIGF, BIGF};

  for (int it = 0; it < jn; ++it) {
    int j = j0 + it;
    if (it + 1 < jn) {  // prefetch next B into alt buffer (overlaps compute)
      const char* gB = (const char*)pB + (size_t)(j+1) * 128 * 256;
      char* dst = (char*)lB[(it+1) & 1];
      #pragma unroll
      for (int rnd = 0; rnd < 4; ++rnd) {
        int row = rnd*32 + rowg;
        g2l16(gB + row*256 + (cb ^ ((row&7)<<4)), dst + row*256 + cb);
      }
    }
    // d2v early: latency hides under the MFMA loop below
    f32x4 d2v[2];
    #pragma unroll
    for (int np = 0; np < 2; ++np)
      d2v[np] = *(const f32x4*)&d2[j*128 + wc*32 + np*16 + rb];

    const char* bufB = (const char*)lB[it & 1];
    f32x4 acc[2][4] = {};               // acc[np][ma]
    #pragma unroll
    for (int ks = 0; ks < 4; ++ks) {
      int cbase = ks*64 + (hq << 4);
      bf16x8 bF[2];
      #pragma unroll
      for (int np = 0; np < 2; ++np)
        bF[np] = *(const bf16x8*)(bufB + (wc*32 + np*16 + lcol)*256 + (cbase ^ rsw));
      #pragma unroll
      for (int np = 0; np < 2; ++np)
        #pragma unroll
        for (int ma = 0; ma < 4; ++ma)
          acc[np][ma] = __builtin_amdgcn_mfma_f32_16x16x32_bf16(bF[np], aF[ma*4+ks], acc[np][ma], 0, 0, 0);
    }

    // epilogue in t-space: t = d2[col] - 2*dot; min accumulates in mPart regs
    if (j != tM) {                      // non-diagonal col-tile (uniform branch)
      #pragma unroll
      for (int ma = 0; ma < 4; ++ma)
        #pragma unroll
        for (int np = 0; np < 2; ++np)
          #pragma unroll
          for (int reg = 0; reg < 4; ++reg)
            mPart[ma] = fminf(mPart[ma], fmaf(-2.f, acc[np][ma][reg], d2v[np][reg]));
    } else {                            // diagonal tile (once per block)
      #pragma unroll
      for (int ma = 0; ma < 4; ++ma) {
        int gi = tM*128 + mh*64 + ma*16 + lcol;
        #pragma unroll
        for (int np = 0; np < 2; ++np)
          #pragma unroll
          for (int reg = 0; reg < 4; ++reg) {
            int gj = j*128 + wc*32 + np*16 + rb + reg;
            float t = fmaf(-2.f, acc[np][ma][reg], d2v[np][reg]);
            if (gi == gj)
              pos[gi] = sqrtf(fmaxf(d1[gi] + t, 0.f) + 1e-6f) + 1e-8f;
            else
              mPart[ma] = fminf(mPart[ma], t);
          }
      }
    }
    __syncthreads();                    // next buffer staged + all reads done
  }

  // final reduce: over hq via shuffles, over the 8 (mh,wc) waves via LDS
  #pragma unroll
  for (int ma = 0; ma < 4; ++ma) {
    float u = mPart[ma];
    u = fminf(u, __shfl_xor(u, 16));
    u = fminf(u, __shfl_xor(u, 32));
    mPart[ma] = u;
  }
  __syncthreads();
  float* sm = (float*)lB;               // scratch [8][64]
  if (hq == 0) {
    #pragma unroll
    for (int ma = 0; ma < 4; ++ma)
      sm[(mh*4 + wc)*64 + ma*16 + lcol] = mPart[ma];
  }
  __syncthreads();
  if (tid < 128) {
    int mh2 = tid >> 6, rloc = tid & 63;
    float u = fminf(fminf(sm[(mh2*4+0)*64 + rloc], sm[(mh2*4+1)*64 + rloc]),
                    fminf(sm[(mh2*4+2)*64 + rloc], sm[(mh2*4+3)*64 + rloc]));
    int row = tM*128 + tid;
    pmin[g*NPAD + row] = sqrtf(fmaxf(d1[row] + u, 0.f) + 1e-6f) + 1e-8f;
  }
}

// -------- finalize: min over group partials (+ diag+10 cand), mean relu --------
__global__ __launch_bounds__(1024) void fin_k(const float* __restrict__ pos,
                                              const float* __restrict__ pmin,
                                              float* __restrict__ out) {
  float s = 0.f;
  for (int i = threadIdx.x*4; i < NPTS; i += 4096) {
    f32x4 p = *(const f32x4*)&pos[i];
    f32x4 mn;
    #pragma unroll
    for (int jj = 0; jj < 4; ++jj) mn[jj] = p[jj] + 10.f;
    #pragma unroll
    for (int gg = 0; gg < NG; ++gg) {
      f32x4 pm = *(const f32x4*)&pmin[gg*NPAD + i];
      #pragma unroll
      for (int jj = 0; jj < 4; ++jj) mn[jj] = fminf(mn[jj], pm[jj]);
    }
    #pragma unroll
    for (int jj = 0; jj < 4; ++jj)
      s += fmaxf(1.0f + p[jj] - mn[jj], 0.f);
  }
  for (int off = 1; off < 64; off <<= 1) s += __shfl_xor(s, off);
  __shared__ float red[16];
  if ((threadIdx.x & 63) == 0) red[threadIdx.x >> 6] = s;
  __syncthreads();
  if (threadIdx.x == 0) {
    float t = 0.f;
    #pragma unroll
    for (int k = 0; k < 16; ++k) t += red[k];
    out[0] = t / (float)NPTS;
  }
}

extern "C" void kernel_launch(void* const* d_in, const int* in_sizes, int n_in,
                              void* d_out, int out_size, void* d_ws, size_t ws_size,
                              hipStream_t stream) {
  const float* feat1 = (const float*)d_in[0];
  const float* feat2 = (const float*)d_in[1];
  const float* aflow = (const float*)d_in[2];

  char* ws = (char*)d_ws;
  ushort* aB = (ushort*)ws;                                   // NPAD*128 bf16
  ushort* pB = aB + (size_t)NPAD * 128;                       // NPAD*128 bf16
  float*  d1 = (float*)(pB + (size_t)NPAD * 128);             // NPAD f32
  float*  d2 = d1 + NPAD;
  float*  pos = d2 + NPAD;
  float*  pmin = pos + NPAD;                                  // NG*NPAD f32

  hipMemsetAsync(d2, 0, NPTS * sizeof(float), stream);        // slab atomics base
  hipLaunchKernelGGL(fused_k, dim3(SLABB + CROPB + 1), dim3(1024), 0, stream,
                     feat1, feat2, aflow, aB, pB, d1, d2);
  hipLaunchKernelGGL(gemmp_k, dim3(NBLK), dim3(512), 0, stream,
                     aB, pB, d1, d2, pos, pmin);
  hipLaunchKernelGGL(fin_k, dim3(1), dim3(1024), 0, stream,
                     pos, pmin, (float*)d_out);
}

// Round 18
// 88.440 us; speedup vs baseline: 3.1826x; 1.1653x over previous
//
#include <hip/hip_runtime.h>
#include <stdint.h>

#define Hh 192
#define Ww 192
#define HW 36864            // 192*192
#define CROPW 38
#define CW2 1444            // 38*38
#define CROPOFF 77
#define NPTS 11552          // 8*38*38
#define NPAD 11776          // 92*128
#define NMT 92              // 128-row tiles
#define NCT 92              // 128-col tiles
#define NG 5                // col-tile groups
#define JPB 19              // col-tiles per group (last group gets 16)
#define NBLK (NG*NMT)       // 460 blocks
#define SLABB 512           // 8 b * 64 channel-pairs
#define CROPB 304           // 38*8 crop blocks
#define BIGF 3.0e38f

typedef short bf16x8 __attribute__((ext_vector_type(8)));
typedef float f32x4 __attribute__((ext_vector_type(4)));
typedef uint32_t u32x4 __attribute__((ext_vector_type(4)));
typedef unsigned short ushort;

__device__ __forceinline__ ushort f2bf(float f) {
  uint32_t b = __float_as_uint(f);
  uint32_t r = b + 0x7fffu + ((b >> 16) & 1u);
  return (ushort)(r >> 16);
}
__device__ __forceinline__ float bf2f(ushort u) {
  return __uint_as_float(((uint32_t)u) << 16);
}

__device__ __forceinline__ void g2l16(const void* g, void* l) {
  __builtin_amdgcn_global_load_lds(
      (const __attribute__((address_space(1))) unsigned int*)g,
      (__attribute__((address_space(3))) unsigned int*)l, 16, 0, 0);
}

// ---- fused sampler: slab blocks (feat2->pB,d2) + crop blocks (feat1->aB,d1) ----
// (R12-proven, unchanged)
__global__ __launch_bounds__(1024) void fused_k(
    const float* __restrict__ feat1, const float* __restrict__ feat2,
    const float* __restrict__ aflow,
    ushort* __restrict__ aB, ushort* __restrict__ pB,
    float* __restrict__ d1, float* __restrict__ d2) {
  __shared__ __align__(16) uint32_t plane[HW];   // 144 KB (slab) / reused by crop
  int bid = blockIdx.x;
  int t = threadIdx.x;

  if (bid < SLABB) {
    // ---------------- slab: (b, channel-pair) ----------------
    int b = bid >> 6, c = (bid & 63) * 2;
    const float* srcA = feat2 + ((size_t)(b*128 + c)) * HW;
    const float* srcB = srcA + HW;
    #pragma unroll
    for (int k = 0; k < 9; ++k) {
      int i = (k*1024 + t) * 4;
      f32x4 va = *(const f32x4*)(srcA + i);
      f32x4 vb = *(const f32x4*)(srcB + i);
      u32x4 pk;
      #pragma unroll
      for (int j = 0; j < 4; ++j)
        pk[j] = (uint32_t)f2bf(va[j]) | ((uint32_t)f2bf(vb[j]) << 16);
      *(u32x4*)&plane[i] = pk;
    }
    __syncthreads();
    int pbase = b*CW2;
    #pragma unroll
    for (int it = 0; it < 2; ++it) {
      int p = it*1024 + t;
      if (p < CW2) {
        int r = p / CROPW, cx = p % CROPW;
        int y = CROPOFF + r, x = CROPOFF + cx;
        float ax = aflow[((b*2 + 0)*Hh + y)*Ww + x];
        float ay = aflow[((b*2 + 1)*Hh + y)*Ww + x];
        // replicate reference's normalize->denormalize round trip
        float gxn = ax * (2.0f/(Ww-1)) - 1.0f;
        float gyn = ay * (2.0f/(Hh-1)) - 1.0f;
        float gx = (gxn + 1.0f) * 0.5f * (Ww-1);
        float gy = (gyn + 1.0f) * 0.5f * (Hh-1);
        // clamp base cell to 190: gx==191 shifts weight to the x=191 tap
        int xi = min((int)floorf(gx), Ww-2);
        int yi = min((int)floorf(gy), Hh-2);
        float wx1 = gx - (float)xi, wx0 = 1.f - wx1;
        float wy1 = gy - (float)yi, wy0 = 1.f - wy1;
        int cell = yi*Ww + xi;
        uint32_t u00 = plane[cell];
        uint32_t u01 = plane[cell + 1];
        uint32_t u10 = plane[cell + Ww];
        uint32_t u11 = plane[cell + Ww + 1];
        float v0 = wy0*(wx0*bf2f((ushort)u00) + wx1*bf2f((ushort)u01))
                 + wy1*(wx0*bf2f((ushort)u10) + wx1*bf2f((ushort)u11));
        float v1 = wy0*(wx0*bf2f((ushort)(u00>>16)) + wx1*bf2f((ushort)(u01>>16)))
                 + wy1*(wx0*bf2f((ushort)(u10>>16)) + wx1*bf2f((ushort)(u11>>16)));
        ushort q0 = f2bf(v0), q1 = f2bf(v1);
        *(uint32_t*)&pB[(size_t)(pbase + p)*128 + c] = (uint32_t)q0 | ((uint32_t)q1 << 16);
        float f0 = bf2f(q0), f1 = bf2f(q1);
        atomicAdd(&d2[pbase + p], f0*f0 + f1*f1);
      }
    }
  } else if (bid < SLABB + CROPB) {
    // ---------------- crop row: feat1 -> aB (channel-last bf16) + d1 ----------
    ushort* lsh = (ushort*)plane;       // 38*136 ushorts
    int rb2 = bid - SLABB;
    int b = rb2 / CROPW, r = rb2 % CROPW;
    int y = CROPOFF + r;
    {
      int xo = t & 63, cg = t >> 6;     // 38 active lanes; 16 groups x 8 ch
      if (xo < CROPW) {
        const float* src = feat1 + ((size_t)b*128*HW) + (size_t)y*Ww + CROPOFF + xo;
        #pragma unroll
        for (int k = 0; k < 8; ++k) {
          int cc = cg + k*16;
          lsh[xo*136 + cc] = f2bf(src[(size_t)cc*HW]);
        }
      }
    }
    __syncthreads();
    int chunk = t & 7, p = t >> 3;      // 128 p-slots, 38 active
    if (p < CROPW) {
      int idx = b*CW2 + r*CROPW + p;
      ushort* dst = aB + (size_t)idx*128 + chunk*16;
      *(bf16x8*)dst       = *(const bf16x8*)&lsh[p*136 + chunk*16];
      *(bf16x8*)(dst + 8) = *(const bf16x8*)&lsh[p*136 + chunk*16 + 8];
      float s = 0.f;
      #pragma unroll
      for (int j = 0; j < 16; ++j) {
        float v = bf2f(lsh[p*136 + chunk*16 + j]);
        s += v*v;
      }
      s += __shfl_xor(s, 1); s += __shfl_xor(s, 2); s += __shfl_xor(s, 4);
      if (chunk == 0) d1[idx] = s;
    }
  } else {
    // ---------------- pad rows: zero aB/pB, d1=0, d2=big ----------------
    if (t < NPAD - NPTS) {
      int row = NPTS + t;
      u32x4 z = {0,0,0,0};
      #pragma unroll
      for (int c = 0; c < 8; ++c) {
        *(u32x4*)&aB[(size_t)row*128 + c*16] = z;
        *(u32x4*)&aB[(size_t)row*128 + c*16 + 8] = z;
        *(u32x4*)&pB[(size_t)row*128 + c*16] = z;
        *(u32x4*)&pB[(size_t)row*128 + c*16 + 8] = z;
      }
      d1[row] = 0.f;
      d2[row] = 1e30f;
    }
  }
}

// ---- persistent fused GEMM (exact R12 structure): A in regs, B LDS dbuf ------
// 256 thr, 4 waves as 1M x 4N strips of the 128x128 block tile; 2 blocks/CU.
// ONE delta vs R12: group's d2 slice preloaded to LDS once (9.7 KB, broadcast
// reads in-loop) instead of 2 global f32x4 loads per thread per iter.
// Swapped MFMA: anchor in lane&15. Swizzle (row&7)<<4 both-sides. No setprio.
__global__ __launch_bounds__(256, 2) void gemmp_k(
    const ushort* __restrict__ aB, const ushort* __restrict__ pB,
    const float* __restrict__ d1, const float* __restrict__ d2,
    float* __restrict__ pos, float* __restrict__ pmin) {
  __shared__ __align__(16) ushort lB[2][128*128];   // 2 x 32 KB
  __shared__ __align__(16) float d2s[JPB*128];      // 9.5 KB group d2 slice

  // m204 bijective chunked XCD swizzle: nwg=460, q=57, r=4
  int bid = blockIdx.x;
  int xcd = bid & 7, kk = bid >> 3;
  int start = (xcd < 4) ? xcd*58 : 232 + (xcd-4)*57;
  int L = start + kk;
  int g = L / NMT, tM = L % NMT;
  int j0 = g * JPB;
  int jn = (NCT - j0 < JPB) ? (NCT - j0) : JPB;

  int tid = threadIdx.x;
  int rowg = tid >> 4, cb = (tid & 15) << 4;
  int w = tid >> 6, l = tid & 63;
  int wc = w;                           // 4 N-strips of 32 cols; waves share M=128
  int lcol = l & 15, hq = l >> 4, rb = hq << 2;
  int rsw = (lcol & 7) << 4;

  {  // stage B0 (swizzled source, linear dest): 128 rows x 256 B
    const char* gB = (const char*)pB + (size_t)j0 * 128 * 256;
    #pragma unroll
    for (int rnd = 0; rnd < 8; ++rnd) {
      int row = rnd*16 + rowg;
      g2l16(gB + row*256 + (cb ^ ((row&7)<<4)), (char*)lB[0] + row*256 + cb);
    }
  }

  // preload group d2 slice (coalesced, once per block)
  for (int i = tid; i < jn*128; i += 256) d2s[i] = d2[j0*128 + i];

  // hoist A fragments once: row = tM*128 + ma*16 + lcol (ma=0..7)
  bf16x8 aF[32];                        // [ma*4+ks], 128 VGPR
  {
    const char* gA = (const char*)aB + ((size_t)(tM*128 + lcol))*256 + hq*16;
    #pragma unroll
    for (int ma = 0; ma < 8; ++ma)
      #pragma unroll
      for (int ks = 0; ks < 4; ++ks)
        aF[ma*4+ks] = *(const bf16x8*)(gA + ma*16*256 + ks*64);
  }
  __syncthreads();   // drains vmcnt (B0 + aF) + d2s visible

  float mPart[8] = {BIGF,BIGF,BIGF,BIGF,BIGF,BIGF,BIGF,BIGF};

  for (int it = 0; it < jn; ++it) {
    int j = j0 + it;
    if (it + 1 < jn) {  // prefetch next B into alt buffer (overlaps compute)
      const char* gB = (const char*)pB + (size_t)(j+1) * 128 * 256;
      char* dst = (char*)lB[(it+1) & 1];
      #pragma unroll
      for (int rnd = 0; rnd < 8; ++rnd) {
        int row = rnd*16 + rowg;
        g2l16(gB + row*256 + (cb ^ ((row&7)<<4)), dst + row*256 + cb);
      }
    }
    // d2v from LDS (broadcast: 4 distinct addrs/wave, conflict-free)
    f32x4 d2v[2];
    #pragma unroll
    for (int np = 0; np < 2; ++np)
      d2v[np] = *(const f32x4*)&d2s[it*128 + wc*32 + np*16 + rb];

    const char* bufB = (const char*)lB[it & 1];
    f32x4 acc[2][8] = {};               // acc[np][ma]
    #pragma unroll
    for (int ks = 0; ks < 4; ++ks) {
      int cbase = ks*64 + (hq << 4);
      bf16x8 bF[2];
      #pragma unroll
      for (int np = 0; np < 2; ++np)
        bF[np] = *(const bf16x8*)(bufB + (wc*32 + np*16 + lcol)*256 + (cbase ^ rsw));
      #pragma unroll
      for (int np = 0; np < 2; ++np)
        #pragma unroll
        for (int ma = 0; ma < 8; ++ma)
          acc[np][ma] = __builtin_amdgcn_mfma_f32_16x16x32_bf16(bF[np], aF[ma*4+ks], acc[np][ma], 0, 0, 0);
    }

    // epilogue in t-space: t = d2[col] - 2*dot; min accumulates in mPart regs
    if (j != tM) {                      // non-diagonal col-tile (uniform branch)
      #pragma unroll
      for (int ma = 0; ma < 8; ++ma)
        #pragma unroll
        for (int np = 0; np < 2; ++np)
          #pragma unroll
          for (int reg = 0; reg < 4; ++reg)
            mPart[ma] = fminf(mPart[ma], fmaf(-2.f, acc[np][ma][reg], d2v[np][reg]));
    } else {                            // diagonal tile (once per block)
      #pragma unroll
      for (int ma = 0; ma < 8; ++ma) {
        int gi = tM*128 + ma*16 + lcol;
        #pragma unroll
        for (int np = 0; np < 2; ++np)
          #pragma unroll
          for (int reg = 0; reg < 4; ++reg) {
            int gj = j*128 + wc*32 + np*16 + rb + reg;
            float t = fmaf(-2.f, acc[np][ma][reg], d2v[np][reg]);
            if (gi == gj)
              pos[gi] = sqrtf(fmaxf(d1[gi] + t, 0.f) + 1e-6f) + 1e-8f;
            else
              mPart[ma] = fminf(mPart[ma], t);
          }
      }
    }
    __syncthreads();                    // next buffer staged + all reads done
  }

  // final reduce: over hq via shuffles, over the 4 col-strip waves via LDS
  #pragma unroll
  for (int ma = 0; ma < 8; ++ma) {
    float u = mPart[ma];
    u = fminf(u, __shfl_xor(u, 16));
    u = fminf(u, __shfl_xor(u, 32));
    mPart[ma] = u;
  }
  __syncthreads();
  float* sm = (float*)lB;               // scratch [4][128]
  if (hq == 0) {
    #pragma unroll
    for (int ma = 0; ma < 8; ++ma)
      sm[wc*128 + ma*16 + lcol] = mPart[ma];
  }
  __syncthreads();
  if (tid < 128) {
    int row = tM*128 + tid;
    float u = fminf(fminf(sm[tid], sm[128 + tid]),
                    fminf(sm[256 + tid], sm[384 + tid]));
    pmin[g*NPAD + row] = sqrtf(fmaxf(d1[row] + u, 0.f) + 1e-6f) + 1e-8f;
  }
}

// -------- finalize: min over group partials (+ diag+10 cand), mean relu --------
__global__ __launch_bounds__(1024) void fin_k(const float* __restrict__ pos,
                                              const float* __restrict__ pmin,
                                              float* __restrict__ out) {
  float s = 0.f;
  for (int i = threadIdx.x*4; i < NPTS; i += 4096) {
    f32x4 p = *(const f32x4*)&pos[i];
    f32x4 mn;
    #pragma unroll
    for (int jj = 0; jj < 4; ++jj) mn[jj] = p[jj] + 10.f;
    #pragma unroll
    for (int gg = 0; gg < NG; ++gg) {
      f32x4 pm = *(const f32x4*)&pmin[gg*NPAD + i];
      #pragma unroll
      for (int jj = 0; jj < 4; ++jj) mn[jj] = fminf(mn[jj], pm[jj]);
    }
    #pragma unroll
    for (int jj = 0; jj < 4; ++jj)
      s += fmaxf(1.0f + p[jj] - mn[jj], 0.f);
  }
  for (int off = 1; off < 64; off <<= 1) s += __shfl_xor(s, off);
  __shared__ float red[16];
  if ((threadIdx.x & 63) == 0) red[threadIdx.x >> 6] = s;
  __syncthreads();
  if (threadIdx.x == 0) {
    float t = 0.f;
    #pragma unroll
    for (int k = 0; k < 16; ++k) t += red[k];
    out[0] = t / (float)NPTS;
  }
}

extern "C" void kernel_launch(void* const* d_in, const int* in_sizes, int n_in,
                              void* d_out, int out_size, void* d_ws, size_t ws_size,
                              hipStream_t stream) {
  const float* feat1 = (const float*)d_in[0];
  const float* feat2 = (const float*)d_in[1];
  const float* aflow = (const float*)d_in[2];

  char* ws = (char*)d_ws;
  ushort* aB = (ushort*)ws;                                   // NPAD*128 bf16
  ushort* pB = aB + (size_t)NPAD * 128;                       // NPAD*128 bf16
  float*  d1 = (float*)(pB + (size_t)NPAD * 128);             // NPAD f32
  float*  d2 = d1 + NPAD;
  float*  pos = d2 + NPAD;
  float*  pmin = pos + NPAD;                                  // NG*NPAD f32

  hipMemsetAsync(d2, 0, NPTS * sizeof(float), stream);        // slab atomics base
  hipLaunchKernelGGL(fused_k, dim3(SLABB + CROPB + 1), dim3(1024), 0, stream,
                     feat1, feat2, aflow, aB, pB, d1, d2);
  hipLaunchKernelGGL(gemmp_k, dim3(NBLK), dim3(256), 0, stream,
                     aB, pB, d1, d2, pos, pmin);
  hipLaunchKernelGGL(fin_k, dim3(1), dim3(1024), 0, stream,
                     pos, pmin, (float*)d_out);
}